// Round 1
// baseline (327.621 us; speedup 1.0000x reference)
//
#include <hip/hip_runtime.h>
#include <math.h>

// Problem constants
#define BB 4
#define GG 8
#define CG 32      // IN_W == OUT_W
#define HH 32
#define WW 32
#define KW 7
#define PAD 3
#define HP 38      // H + 2*PAD
#define NHEADS 4
#define MTOT 392   // G*K*K
#define QN 32      // G*HEADS queries per spatial position

// ---------------------------------------------------------------------------
// Q = grouped 1x1 conv, 128 out-channels per group.
// Qbuf layout: [b][h][w][ qi*32 + c ] where qi = g*4 + head  (flat 1024/pos)
// ---------------------------------------------------------------------------
__global__ __launch_bounds__(256) void q_kernel(const float* __restrict__ x,
                                                const float* __restrict__ wq,
                                                const float* __restrict__ bq,
                                                float* __restrict__ Qbuf) {
    int bid = blockIdx.x;
    int h = bid & 31;
    int g = (bid >> 5) & 7;
    int b = bid >> 8;

    __shared__ float xrow[32 * 32];        // [i][w]
    __shared__ float wql[128 * 33];        // [oc][i], +1 pad kills bank conflict

    int t = threadIdx.x;
    for (int idx = t; idx < 1024; idx += 256) {
        int i = idx >> 5, w = idx & 31;
        xrow[idx] = x[(((size_t)b * 256 + g * 32 + i) * 32 + h) * 32 + w];
    }
    for (int idx = t; idx < 4096; idx += 256) {
        int oc = idx >> 5, i = idx & 31;
        wql[oc * 33 + i] = wq[((size_t)g * 128 + oc) * 32 + i];
    }
    __syncthreads();

    int oc = t & 127;      // consecutive lanes -> consecutive oc (coalesced store)
    int w0 = t >> 7;       // 0..1
    float bias = bq[g * 128 + oc];
    for (int it = 0; it < 16; ++it) {
        int w = w0 + it * 2;
        float acc = bias;
#pragma unroll
        for (int i = 0; i < 32; ++i)
            acc = fmaf(xrow[i * 32 + w], wql[oc * 33 + i], acc);
        Qbuf[(((size_t)(b * 32 + h) * 32 + w) * 8 + g) * 128 + oc] = acc;
    }
}

// ---------------------------------------------------------------------------
// K,V = grouped 1x1 conv over the padded 38x38 grid (bias-only at pads).
// Layout: [b][g][hp][wp][c]
// ---------------------------------------------------------------------------
__global__ __launch_bounds__(256) void kv_kernel(const float* __restrict__ x,
                                                 const float* __restrict__ wk,
                                                 const float* __restrict__ bk,
                                                 const float* __restrict__ wv,
                                                 const float* __restrict__ bv,
                                                 float* __restrict__ Kbuf,
                                                 float* __restrict__ Vbuf) {
    int bid = blockIdx.x;
    int hp = bid % 38;
    int g = (bid / 38) & 7;
    int b = bid / (38 * 8);

    __shared__ float xrow[1024];           // [i][w]
    __shared__ float wkl[32 * 33];
    __shared__ float wvl[32 * 33];

    int t = threadIdx.x;
    int h = hp - PAD;
    bool hin = (h >= 0 && h < 32);
    for (int idx = t; idx < 1024; idx += 256) {
        int i = idx >> 5, w = idx & 31;
        xrow[idx] = hin ? x[(((size_t)b * 256 + g * 32 + i) * 32 + h) * 32 + w] : 0.0f;
    }
    for (int idx = t; idx < 1024; idx += 256) {
        int c = idx >> 5, i = idx & 31;
        wkl[c * 33 + i] = wk[((size_t)g * 32 + c) * 32 + i];
        wvl[c * 33 + i] = wv[((size_t)g * 32 + c) * 32 + i];
    }
    __syncthreads();

    int c = t & 31;
    int wp0 = t >> 5;
    float kb = bk[g * 32 + c], vb = bv[g * 32 + c];
    for (int it = 0; it < 5; ++it) {
        int wp = wp0 + it * 8;
        if (wp >= 38) break;
        float ka = kb, va = vb;
        int w = wp - PAD;
        if (w >= 0 && w < 32) {
#pragma unroll
            for (int i = 0; i < 32; ++i) {
                float xv = xrow[i * 32 + w];
                ka = fmaf(xv, wkl[c * 33 + i], ka);
                va = fmaf(xv, wvl[c * 33 + i], va);
            }
        }
        size_t o = ((((size_t)(b * 8 + g) * 38 + hp) * 38 + wp) << 5) + c;
        Kbuf[o] = ka;
        Vbuf[o] = va;
    }
}

// ---------------------------------------------------------------------------
// Fused attention: one block per (b, x, y).
//   thread (qi = t>>3, gp = t&7): 49 scores of query qi against group gp's window
//   softmax reduced over gp lanes (xor 1,2,4); head-sum over lanes (xor 8,16)
//   output phase: thread (g = t>>5, c = t&31) accumulates over 392 keys.
// LDS: kwl[392][36] fp32 (rows 16B-aligned; gp-rows hit disjoint bank quads),
//      aliased by A_l[8][392] after scores are consumed; q_l[32][33].
// Total 60672 B < 64 KB -> 2 blocks/CU.
// ---------------------------------------------------------------------------
__global__ __launch_bounds__(256) void attn_kernel(const float* __restrict__ Qbuf,
                                                   const float* __restrict__ Kbuf,
                                                   const float* __restrict__ Vbuf,
                                                   const float* __restrict__ rel_h,
                                                   const float* __restrict__ rel_w,
                                                   float* __restrict__ out) {
    int bid = blockIdx.x;
    int y = bid & 31;
    int x = (bid >> 5) & 31;
    int b = bid >> 10;

    __shared__ float sbuf[392 * 36 + 32 * 33];
    float* kwl = sbuf;          // [m][36]
    float* A_l = sbuf;          // aliases kwl after scores consumed: [g][392]
    float* q_l = sbuf + 392 * 36;  // [qi][33]

    int t = threadIdx.x;

    // ---- stage K window (all groups) ----
    for (int idx = t; idx < MTOT * 32; idx += 256) {
        int m = idx >> 5, c = idx & 31;
        int gp2 = m / 49;
        int r = m - gp2 * 49;
        int kh = r / 7;
        int kw = r - kh * 7;
        kwl[m * 36 + c] =
            Kbuf[((((size_t)(b * 8 + gp2) * 38 + (x + kh)) * 38 + (y + kw)) << 5) + c];
    }
    // ---- stage Q (1024 floats for this position) ----
    const float* qptr = Qbuf + (size_t)((b * 32 + x) * 32 + y) * 1024;
    for (int idx = t; idx < 1024; idx += 256) {
        q_l[(idx >> 5) * 33 + (idx & 31)] = qptr[idx];
    }
    __syncthreads();

    int gp = t & 7;
    int qi = t >> 3;     // g*4 + head

    // q vector into registers
    float qv[32];
#pragma unroll
    for (int c = 0; c < 32; ++c) qv[c] = q_l[qi * 33 + c];

    // rel_h / rel_w folded into per-query dot terms:
    //   RH[kh] = sum_{c<16} q[c]*rel_h[c][gp][kh];  RW[kw] = sum q[c+16]*rel_w[c][gp][kw]
    float RH[7], RW[7];
#pragma unroll
    for (int k = 0; k < 7; ++k) { RH[k] = 0.f; RW[k] = 0.f; }
    for (int c = 0; c < 16; ++c) {
        float qh = qv[c], qw = qv[c + 16];
#pragma unroll
        for (int k = 0; k < 7; ++k) {
            RH[k] = fmaf(qh, rel_h[c * 56 + gp * 7 + k], RH[k]);
            RW[k] = fmaf(qw, rel_w[c * 56 + gp * 7 + k], RW[k]);
        }
    }

    // ---- scores: 49 keys of group gp ----
    float s[49];
    {
        int m0 = gp * 49;
#pragma unroll
        for (int r = 0; r < 49; ++r) {
            const float* krow = &kwl[(m0 + r) * 36];
            float acc = RH[r / 7] + RW[r % 7];
#pragma unroll
            for (int j = 0; j < 8; ++j) {
                float4 k4 = *(const float4*)(krow + 4 * j);
                acc = fmaf(qv[4 * j + 0], k4.x, acc);
                acc = fmaf(qv[4 * j + 1], k4.y, acc);
                acc = fmaf(qv[4 * j + 2], k4.z, acc);
                acc = fmaf(qv[4 * j + 3], k4.w, acc);
            }
            s[r] = acc;
        }
    }

    // ---- softmax over all 392 (this qi spans 8 gp lanes) ----
    float mx = -1e30f;
#pragma unroll
    for (int r = 0; r < 49; ++r) mx = fmaxf(mx, s[r]);
    mx = fmaxf(mx, __shfl_xor(mx, 1));
    mx = fmaxf(mx, __shfl_xor(mx, 2));
    mx = fmaxf(mx, __shfl_xor(mx, 4));

    float sum = 0.f;
#pragma unroll
    for (int r = 0; r < 49; ++r) {
        s[r] = __expf(s[r] - mx);
        sum += s[r];
    }
    sum += __shfl_xor(sum, 1);
    sum += __shfl_xor(sum, 2);
    sum += __shfl_xor(sum, 4);
    float inv = 1.0f / sum;

    // normalize + head-sum (heads live at lane bits 3..4)
#pragma unroll
    for (int r = 0; r < 49; ++r) {
        float a = s[r] * inv;
        a += __shfl_xor(a, 8);
        a += __shfl_xor(a, 16);
        s[r] = a;
    }

    __syncthreads();   // everyone done reading kwl before aliasing it as A_l

    int head = (t >> 3) & 3;
    int g = t >> 5;
    if (head == 0) {
#pragma unroll
        for (int r = 0; r < 49; ++r) A_l[g * 392 + gp * 49 + r] = s[r];
    }
    __syncthreads();

    // ---- output: thread (go, c); V read straight from L2 (coalesced lines) ----
    int c = t & 31;
    int go = t >> 5;
    const float* Ar = &A_l[go * 392];
    float acc = 0.f;
    for (int gp2 = 0; gp2 < 8; ++gp2) {
        const float* vbase =
            Vbuf + ((((size_t)(b * 8 + gp2) * 38 + x) * 38 + y) << 5) + c;
        int mbase = gp2 * 49;
#pragma unroll
        for (int kh = 0; kh < 7; ++kh) {
#pragma unroll
            for (int kw = 0; kw < 7; ++kw) {
                acc = fmaf(Ar[mbase + kh * 7 + kw], vbase[(kh * 38 + kw) << 5], acc);
            }
        }
    }
    out[((((size_t)(b * 8 + go) * 32 + x) * 32 + y) << 5) + c] = acc;
}

// ---------------------------------------------------------------------------
extern "C" void kernel_launch(void* const* d_in, const int* in_sizes, int n_in,
                              void* d_out, int out_size, void* d_ws, size_t ws_size,
                              hipStream_t stream) {
    const float* x     = (const float*)d_in[0];
    const float* wq    = (const float*)d_in[1];
    const float* bq    = (const float*)d_in[2];
    const float* wk    = (const float*)d_in[3];
    const float* bk    = (const float*)d_in[4];
    const float* wv    = (const float*)d_in[5];
    const float* bv    = (const float*)d_in[6];
    const float* rel_h = (const float*)d_in[7];
    const float* rel_w = (const float*)d_in[8];
    float* out = (float*)d_out;

    float* Qbuf = (float*)d_ws;                       // 4*32*32*1024 = 4,194,304 f
    float* Kbuf = Qbuf + (size_t)4 * 32 * 32 * 1024;  // 4*8*38*38*32 = 1,478,656 f
    float* Vbuf = Kbuf + (size_t)4 * 8 * 38 * 38 * 32;

    hipLaunchKernelGGL(q_kernel, dim3(4 * 8 * 32), dim3(256), 0, stream,
                       x, wq, bq, Qbuf);
    hipLaunchKernelGGL(kv_kernel, dim3(4 * 8 * 38), dim3(256), 0, stream,
                       x, wk, bk, wv, bv, Kbuf, Vbuf);
    hipLaunchKernelGGL(attn_kernel, dim3(4 * 32 * 32), dim3(256), 0, stream,
                       Qbuf, Kbuf, Vbuf, rel_h, rel_w, out);
}

// Round 2
// 249.525 us; speedup vs baseline: 1.3130x; 1.3130x over previous
//
#include <hip/hip_runtime.h>
#include <math.h>

// Problem constants
#define BB 4
#define GG 8
#define CG 32      // IN_W == OUT_W
#define HH 32
#define WW 32
#define KW 7
#define PAD 3
#define HP 38      // H + 2*PAD
#define NHEADS 4
#define MTOT 392   // G*K*K

typedef _Float16 f16;
typedef f16 f16x2 __attribute__((ext_vector_type(2)));
typedef f16 f16x8 __attribute__((ext_vector_type(8)));

union f16x8_cast {
    f16x8 v8;
    f16x2 v2[4];
};

// ---------------------------------------------------------------------------
// Q = grouped 1x1 conv, 128 out-channels per group (fp32).
// Qbuf layout: [b][h][w][ qi*32 + c ], qi = g*4 + head
// ---------------------------------------------------------------------------
__global__ __launch_bounds__(256) void q_kernel(const float* __restrict__ x,
                                                const float* __restrict__ wq,
                                                const float* __restrict__ bq,
                                                float* __restrict__ Qbuf) {
    int bid = blockIdx.x;
    int h = bid & 31;
    int g = (bid >> 5) & 7;
    int b = bid >> 8;

    __shared__ float xrow[32 * 32];        // [i][w]
    __shared__ float wql[128 * 33];        // [oc][i]

    int t = threadIdx.x;
    for (int idx = t; idx < 1024; idx += 256) {
        int i = idx >> 5, w = idx & 31;
        xrow[idx] = x[(((size_t)b * 256 + g * 32 + i) * 32 + h) * 32 + w];
    }
    for (int idx = t; idx < 4096; idx += 256) {
        int oc = idx >> 5, i = idx & 31;
        wql[oc * 33 + i] = wq[((size_t)g * 128 + oc) * 32 + i];
    }
    __syncthreads();

    int oc = t & 127;
    int w0 = t >> 7;
    float bias = bq[g * 128 + oc];
    for (int it = 0; it < 16; ++it) {
        int w = w0 + it * 2;
        float acc = bias;
#pragma unroll
        for (int i = 0; i < 32; ++i)
            acc = fmaf(xrow[i * 32 + w], wql[oc * 33 + i], acc);
        Qbuf[(((size_t)(b * 32 + h) * 32 + w) * 8 + g) * 128 + oc] = acc;
    }
}

// ---------------------------------------------------------------------------
// K (f16 out), V (fp32 out) grouped 1x1 conv over padded 38x38 grid.
// Layout: [b][g][hp][wp][c]
// ---------------------------------------------------------------------------
__global__ __launch_bounds__(256) void kv_kernel(const float* __restrict__ x,
                                                 const float* __restrict__ wk,
                                                 const float* __restrict__ bk,
                                                 const float* __restrict__ wv,
                                                 const float* __restrict__ bv,
                                                 f16* __restrict__ Kbuf,
                                                 float* __restrict__ Vbuf) {
    int bid = blockIdx.x;
    int hp = bid % 38;
    int g = (bid / 38) & 7;
    int b = bid / (38 * 8);

    __shared__ float xrow[1024];           // [i][w]
    __shared__ float wkl[32 * 33];
    __shared__ float wvl[32 * 33];

    int t = threadIdx.x;
    int h = hp - PAD;
    bool hin = (h >= 0 && h < 32);
    for (int idx = t; idx < 1024; idx += 256) {
        int i = idx >> 5, w = idx & 31;
        xrow[idx] = hin ? x[(((size_t)b * 256 + g * 32 + i) * 32 + h) * 32 + w] : 0.0f;
    }
    for (int idx = t; idx < 1024; idx += 256) {
        int c = idx >> 5, i = idx & 31;
        wkl[c * 33 + i] = wk[((size_t)g * 32 + c) * 32 + i];
        wvl[c * 33 + i] = wv[((size_t)g * 32 + c) * 32 + i];
    }
    __syncthreads();

    int c = t & 31;
    int wp0 = t >> 5;
    float kb = bk[g * 32 + c], vb = bv[g * 32 + c];
    for (int it = 0; it < 5; ++it) {
        int wp = wp0 + it * 8;
        if (wp >= 38) break;
        float ka = kb, va = vb;
        int w = wp - PAD;
        if (w >= 0 && w < 32) {
#pragma unroll
            for (int i = 0; i < 32; ++i) {
                float xv = xrow[i * 32 + w];
                ka = fmaf(xv, wkl[c * 33 + i], ka);
                va = fmaf(xv, wvl[c * 33 + i], va);
            }
        }
        size_t o = ((((size_t)(b * 8 + g) * 38 + hp) * 38 + wp) << 5) + c;
        Kbuf[o] = (f16)ka;
        Vbuf[o] = va;
    }
}

// ---------------------------------------------------------------------------
// Fused attention, f16 K/Q in LDS + v_dot2_f32_f16.
// LDS: kwl f16 [392][40] (rows 80 B; gp-rows land on disjoint bank quads ->
//      conflict-free b128), q_l f16 [32][40]; A_l fp32 [8][392] aliases kwl.
// Total 33,920 B -> 4 blocks/CU.
// ---------------------------------------------------------------------------
__global__ __launch_bounds__(256) void attn_kernel(const float* __restrict__ Qbuf,
                                                   const f16* __restrict__ Kbuf,
                                                   const float* __restrict__ Vbuf,
                                                   const float* __restrict__ rel_h,
                                                   const float* __restrict__ rel_w,
                                                   float* __restrict__ out) {
    int bid = blockIdx.x;
    int y = bid & 31;
    int x = (bid >> 5) & 31;
    int b = bid >> 10;

    __shared__ __align__(16) unsigned char smem[392 * 80 + 32 * 80];
    f16x2* kwl = (f16x2*)smem;               // row stride 20 f16x2 (80 B)
    f16x2* q_l = (f16x2*)(smem + 392 * 80);  // row stride 20 f16x2
    float* A_l = (float*)smem;               // alias after barrier: [g][392]

    int t = threadIdx.x;

    // ---- stage K window (f16, all groups) ----
    const f16x2* __restrict__ Ks = (const f16x2*)Kbuf;
    for (int idx = t; idx < MTOT * 16; idx += 256) {
        int m = idx >> 4, p = idx & 15;
        int gp2 = m / 49;
        int r = m - gp2 * 49;
        int kh = r / 7;
        int kw = r - kh * 7;
        kwl[m * 20 + p] =
            Ks[((((size_t)(b * 8 + gp2) * 38 + (x + kh)) * 38 + (y + kw)) << 4) + p];
    }
    // ---- stage Q (converted to f16) ----
    const float2* __restrict__ qf =
        (const float2*)(Qbuf + (size_t)((b * 32 + x) * 32 + y) * 1024);
    for (int idx = t; idx < 512; idx += 256) {
        float2 v = qf[idx];
        f16x2 hh;
        hh.x = (f16)v.x;
        hh.y = (f16)v.y;
        q_l[(idx >> 4) * 20 + (idx & 15)] = hh;
    }
    __syncthreads();

    int gp = t & 7;
    int qi = t >> 3;     // g*4 + head

    // q vector into registers (16 half2 = 32 ch)
    f16x2 qh[16];
    {
        const f16x8* qrow = (const f16x8*)(q_l + qi * 20);
#pragma unroll
        for (int j = 0; j < 4; ++j) {
            f16x8_cast u;
            u.v8 = qrow[j];
#pragma unroll
            for (int e = 0; e < 4; ++e) qh[j * 4 + e] = u.v2[e];
        }
    }

    // rel terms folded per query: RH[kh] = sum_{c<16} q[c]*rel_h[c][gp][kh]
    float RH[7], RW[7];
#pragma unroll
    for (int k = 0; k < 7; ++k) { RH[k] = 0.f; RW[k] = 0.f; }
#pragma unroll
    for (int c = 0; c < 16; ++c) {
        float qhc = (float)qh[c >> 1][c & 1];
        float qwc = (float)qh[(c + 16) >> 1][c & 1];
#pragma unroll
        for (int k = 0; k < 7; ++k) {
            RH[k] = fmaf(qhc, rel_h[c * 56 + gp * 7 + k], RH[k]);
            RW[k] = fmaf(qwc, rel_w[c * 56 + gp * 7 + k], RW[k]);
        }
    }

    // ---- scores: 49 keys of group gp via v_dot2_f32_f16 ----
    float s[49];
    {
        int m0 = gp * 49;
#pragma unroll
        for (int kh = 0; kh < 7; ++kh) {
#pragma unroll
            for (int kw = 0; kw < 7; ++kw) {
                int r = kh * 7 + kw;
                const f16x8* krow = (const f16x8*)(kwl + (m0 + r) * 20);
                float acc = RH[kh] + RW[kw];
#pragma unroll
                for (int j = 0; j < 4; ++j) {
                    f16x8_cast u;
                    u.v8 = krow[j];
#pragma unroll
                    for (int e = 0; e < 4; ++e)
                        acc = __builtin_amdgcn_fdot2(qh[j * 4 + e], u.v2[e], acc, false);
                }
                s[r] = acc;
            }
        }
    }

    // ---- softmax over all 392 (qi spans 8 gp lanes) ----
    float mx = -1e30f;
#pragma unroll
    for (int r = 0; r < 49; ++r) mx = fmaxf(mx, s[r]);
    mx = fmaxf(mx, __shfl_xor(mx, 1));
    mx = fmaxf(mx, __shfl_xor(mx, 2));
    mx = fmaxf(mx, __shfl_xor(mx, 4));

    float sum = 0.f;
#pragma unroll
    for (int r = 0; r < 49; ++r) {
        s[r] = __expf(s[r] - mx);
        sum += s[r];
    }
    sum += __shfl_xor(sum, 1);
    sum += __shfl_xor(sum, 2);
    sum += __shfl_xor(sum, 4);
    float inv = 1.0f / sum;

    // normalize + head-sum (head bits at lane bits 3..4)
#pragma unroll
    for (int r = 0; r < 49; ++r) {
        float a = s[r] * inv;
        a += __shfl_xor(a, 8);
        a += __shfl_xor(a, 16);
        s[r] = a;
    }

    __syncthreads();   // kwl fully consumed before aliasing as A_l

    int head = (t >> 3) & 3;
    int g = t >> 5;
    if (head == 0) {
#pragma unroll
        for (int r = 0; r < 49; ++r) A_l[g * 392 + gp * 49 + r] = s[r];
    }
    __syncthreads();

    // ---- output: thread (go, c); V fp32 straight from L2 ----
    int c = t & 31;
    int go = t >> 5;
    const float* Ar = &A_l[go * 392];
    float acc = 0.f;
    for (int gp2 = 0; gp2 < 8; ++gp2) {
        const float* vbase =
            Vbuf + ((((size_t)(b * 8 + gp2) * 38 + x) * 38 + y) << 5) + c;
        int mbase = gp2 * 49;
#pragma unroll
        for (int kh = 0; kh < 7; ++kh) {
#pragma unroll
            for (int kw = 0; kw < 7; ++kw) {
                acc = fmaf(Ar[mbase + kh * 7 + kw], vbase[(kh * 38 + kw) << 5], acc);
            }
        }
    }
    out[((((size_t)(b * 8 + go) * 32 + x) * 32 + y) << 5) + c] = acc;
}

// ---------------------------------------------------------------------------
extern "C" void kernel_launch(void* const* d_in, const int* in_sizes, int n_in,
                              void* d_out, int out_size, void* d_ws, size_t ws_size,
                              hipStream_t stream) {
    const float* x     = (const float*)d_in[0];
    const float* wq    = (const float*)d_in[1];
    const float* bq    = (const float*)d_in[2];
    const float* wk    = (const float*)d_in[3];
    const float* bk    = (const float*)d_in[4];
    const float* wv    = (const float*)d_in[5];
    const float* bv    = (const float*)d_in[6];
    const float* rel_h = (const float*)d_in[7];
    const float* rel_w = (const float*)d_in[8];
    float* out = (float*)d_out;

    // ws layout (bytes):
    //   Qbuf fp32: 4*32*32*1024*4      = 16,777,216
    //   Kbuf f16 : 4*8*38*38*32*2      =  2,957,312
    //   Vbuf fp32: 4*8*38*38*32*4      =  5,914,624
    unsigned char* ws = (unsigned char*)d_ws;
    float* Qbuf = (float*)ws;
    f16*   Kbuf = (f16*)(ws + 16777216);
    float* Vbuf = (float*)(ws + 16777216 + 2957312);

    hipLaunchKernelGGL(q_kernel, dim3(4 * 8 * 32), dim3(256), 0, stream,
                       x, wq, bq, Qbuf);
    hipLaunchKernelGGL(kv_kernel, dim3(4 * 8 * 38), dim3(256), 0, stream,
                       x, wk, bk, wv, bv, Kbuf, Vbuf);
    hipLaunchKernelGGL(attn_kernel, dim3(4 * 32 * 32), dim3(256), 0, stream,
                       Qbuf, Kbuf, Vbuf, rel_h, rel_w, out);
}

// Round 3
// 172.549 us; speedup vs baseline: 1.8987x; 1.4461x over previous
//
#include <hip/hip_runtime.h>
#include <math.h>

typedef _Float16 f16;
typedef _Float16 f16x2 __attribute__((ext_vector_type(2)));
typedef _Float16 f16x4 __attribute__((ext_vector_type(4)));
typedef _Float16 f16x8 __attribute__((ext_vector_type(8)));
typedef float f32x4 __attribute__((ext_vector_type(4)));
typedef float f32x4u __attribute__((ext_vector_type(4), aligned(4)));

#define MFMA16(a, b, c) __builtin_amdgcn_mfma_f32_16x16x32_f16(a, b, c, 0, 0, 0)

// ---------------------------------------------------------------------------
// Prep: rearrange rel_h / rel_w into MFMA-A-operand-friendly f16 tables.
// relhA[64 m2][32 k]: m2 = gp*7+kh (<56), k<16 -> rel_h[k][m2], else 0.
// relwA[64 m2][32 k]: m2 = gp*8+kw, kw<7 && k>=16 -> rel_w[k-16][gp*7+kw], else 0.
// ---------------------------------------------------------------------------
__global__ __launch_bounds__(256) void prep_kernel(const float* __restrict__ rel_h,
                                                   const float* __restrict__ rel_w,
                                                   f16* __restrict__ relhA,
                                                   f16* __restrict__ relwA) {
    int t = threadIdx.x;
    for (int idx = t; idx < 2048; idx += 256) {
        int m2 = idx >> 5, k = idx & 31;
        float hv = 0.f, wvv = 0.f;
        if (m2 < 56 && k < 16) hv = rel_h[k * 56 + m2];
        int kw = m2 & 7, gp = m2 >> 3;
        if (kw < 7 && k >= 16) wvv = rel_w[(k - 16) * 56 + gp * 7 + kw];
        relhA[idx] = (f16)hv;
        relwA[idx] = (f16)wvv;
    }
}

// ---------------------------------------------------------------------------
// Q conv: weights in registers, xrow broadcast b128 reads, f16 output
// Qb[pos][qi][c], pos=(b*32+h)*32+w, qi=g*4+head (oc = head*32+c).
// ---------------------------------------------------------------------------
__global__ __launch_bounds__(256) void q_kernel(const float* __restrict__ x,
                                                const float* __restrict__ wq,
                                                const float* __restrict__ bq,
                                                f16* __restrict__ Qb) {
    int bid = blockIdx.x;
    int h = bid & 31, g = (bid >> 5) & 7, b = bid >> 8;
    __shared__ float xrow[1024];  // [i][w]
    int t = threadIdx.x;
    for (int idx = t; idx < 1024; idx += 256) {
        int i = idx >> 5, w = idx & 31;
        xrow[idx] = x[(((size_t)b * 256 + g * 32 + i) * 32 + h) * 32 + w];
    }
    int oc = t & 127, w0 = t >> 7;
    float wr[32];
    {
        const float4* wp4 = (const float4*)(wq + ((size_t)g * 128 + oc) * 32);
#pragma unroll
        for (int j = 0; j < 8; ++j) {
            float4 v = wp4[j];
            wr[j * 4] = v.x; wr[j * 4 + 1] = v.y; wr[j * 4 + 2] = v.z; wr[j * 4 + 3] = v.w;
        }
    }
    float bias = bq[g * 128 + oc];
    float acc[16];
#pragma unroll
    for (int j = 0; j < 16; ++j) acc[j] = bias;
    __syncthreads();
    for (int i = 0; i < 32; ++i) {
        float wv = wr[i];
        const float4* xr = (const float4*)&xrow[i * 32 + w0 * 16];
#pragma unroll
        for (int j = 0; j < 4; ++j) {
            float4 xv = xr[j];
            acc[j * 4 + 0] = fmaf(wv, xv.x, acc[j * 4 + 0]);
            acc[j * 4 + 1] = fmaf(wv, xv.y, acc[j * 4 + 1]);
            acc[j * 4 + 2] = fmaf(wv, xv.z, acc[j * 4 + 2]);
            acc[j * 4 + 3] = fmaf(wv, xv.w, acc[j * 4 + 3]);
        }
    }
    int qi = g * 4 + (oc >> 5), c = oc & 31;
#pragma unroll
    for (int j = 0; j < 16; ++j) {
        int w = w0 * 16 + j;
        Qb[((size_t)((b * 32 + h) * 32 + w)) * 1024 + qi * 32 + c] = (f16)acc[j];
    }
}

// ---------------------------------------------------------------------------
// K/V conv over padded 38x38: K f16 [b][g][hp][wp][c]; V fp32 transposed
// Vt[b][g][c][hp][wp(40, pad zeroed)]. Weights in registers.
// ---------------------------------------------------------------------------
__global__ __launch_bounds__(256) void kv_kernel(const float* __restrict__ x,
                                                 const float* __restrict__ wk,
                                                 const float* __restrict__ bk,
                                                 const float* __restrict__ wv,
                                                 const float* __restrict__ bv,
                                                 f16* __restrict__ Kb,
                                                 float* __restrict__ Vt) {
    int bid = blockIdx.x;
    int hp = bid % 38, g = (bid / 38) & 7, b = bid / (38 * 8);
    __shared__ float xrow[1024];
    __shared__ float vt[32 * 41];  // row pad 41 breaks 8-way bank conflict
    int t = threadIdx.x;
    int h = hp - 3;
    bool hin = (h >= 0 && h < 32);
    for (int idx = t; idx < 1024; idx += 256) {
        int i = idx >> 5, w = idx & 31;
        xrow[idx] = hin ? x[(((size_t)b * 256 + g * 32 + i) * 32 + h) * 32 + w] : 0.0f;
    }
    if (t < 64) vt[(t >> 1) * 41 + 38 + (t & 1)] = 0.0f;  // zero wp pad
    int c = t & 31, wp0 = t >> 5;
    float wkr[32], wvr[32];
    {
        const float4* k4 = (const float4*)(wk + ((size_t)g * 32 + c) * 32);
        const float4* v4 = (const float4*)(wv + ((size_t)g * 32 + c) * 32);
#pragma unroll
        for (int j = 0; j < 8; ++j) {
            float4 a = k4[j];
            wkr[j * 4] = a.x; wkr[j * 4 + 1] = a.y; wkr[j * 4 + 2] = a.z; wkr[j * 4 + 3] = a.w;
            float4 bb = v4[j];
            wvr[j * 4] = bb.x; wvr[j * 4 + 1] = bb.y; wvr[j * 4 + 2] = bb.z; wvr[j * 4 + 3] = bb.w;
        }
    }
    float kbv = bk[g * 32 + c], vbv = bv[g * 32 + c];
    __syncthreads();
    for (int it = 0; it < 5; ++it) {
        int wp = wp0 + it * 8;
        if (wp >= 38) break;
        float ka = kbv, va = vbv;
        int w = wp - 3;
        if (w >= 0 && w < 32) {
#pragma unroll
            for (int i = 0; i < 32; ++i) {
                float xv = xrow[i * 32 + w];
                ka = fmaf(xv, wkr[i], ka);
                va = fmaf(xv, wvr[i], va);
            }
        }
        Kb[((((size_t)(b * 8 + g) * 38 + hp) * 38 + wp) << 5) + c] = (f16)ka;
        vt[c * 41 + wp] = va;
    }
    __syncthreads();
    for (int idx = t; idx < 1280; idx += 256) {
        int c2 = idx / 40, wp2 = idx % 40;
        Vt[((((size_t)(b * 8 + g) * 32 + c2) * 38 + hp)) * 40 + wp2] = vt[c2 * 41 + wp2];
    }
}

// ---------------------------------------------------------------------------
// MFMA attention: one wave (64 thr) per position.
// m' space = (gp*7+kh)*8 + kw, kw 0..7 (kw=7 masked) -> 448 keys.
// Phase A: RHT/RWT rel tables via 16 mfma.  Phase B: pass1 sums (56 mfma),
// pass2 normalized A8 packed in regs (56 mfma).  Phase C: PV (28 mfma),
// A8 LDS (aliases rel tables), V-fragments streamed from global Vt.
// LDS = 16*456 f16 = 14592 B -> ~11 waves/CU.
// ---------------------------------------------------------------------------
__global__ __launch_bounds__(64, 3) void attn_kernel(const f16* __restrict__ Qb,
                                                     const f16* __restrict__ Kb,
                                                     const float* __restrict__ Vt,
                                                     const f16* __restrict__ relhA,
                                                     const f16* __restrict__ relwA,
                                                     float* __restrict__ out) {
    int bid = blockIdx.x;
    // XCD-locality swizzle: consecutive 512-position chunks per XCD slot
    int pid = (bid & 7) * 512 + (bid >> 3);
    int y = pid & 31, x = (pid >> 5) & 31, b = pid >> 10;

    __shared__ __align__(16) f16 sbuf[16 * 456];  // 14592 B
    f16* RHT = sbuf;             // [64][36] (rows >=56 scratch)
    f16* RWT = sbuf + 64 * 36;   // [64][36]
    f16* Apr = sbuf;             // [16][456] alias, time-separated

    int t = threadIdx.x;
    int l15 = t & 15, quad = t >> 4, kwl = t & 7, p8 = (t >> 3) & 1;
    bool mask7 = (kwl == 7);

    // Q fragments (A-role rows / B-role cols are the same per-lane data)
    f16x8 qf[2];
    {
        const f16x8* qp = (const f16x8*)(Qb + (size_t)pid * 1024);
        qf[0] = qp[l15 * 4 + quad];
        qf[1] = qp[(16 + l15) * 4 + quad];
    }

    // ---- rel tables via mfma: D[m2][qi] ----
#pragma unroll
    for (int rt = 0; rt < 2; ++rt) {
        const f16* ra = rt ? relwA : relhA;
        f16* tab = rt ? RWT : RHT;
#pragma unroll
        for (int Mt2 = 0; Mt2 < 4; ++Mt2) {
            f16x8 af = *(const f16x8*)(ra + (Mt2 * 16 + l15) * 32 + quad * 8);
#pragma unroll
            for (int Nt2 = 0; Nt2 < 2; ++Nt2) {
                f32x4 d = {0.f, 0.f, 0.f, 0.f};
                d = MFMA16(af, qf[Nt2], d);
#pragma unroll
                for (int r = 0; r < 4; ++r)
                    tab[(Mt2 * 16 + quad * 4 + r) * 36 + Nt2 * 16 + l15] = (f16)d[r];
            }
        }
    }
    __syncthreads();

    // ---- pass 1: softmax denominators (no max-sub; |s| << 88) ----
    float fsum[2][4];
#pragma unroll
    for (int m = 0; m < 2; ++m)
#pragma unroll
        for (int r = 0; r < 4; ++r) fsum[m][r] = 0.f;

    for (int nt = 0; nt < 28; ++nt) {
        int ghk = nt * 2 + p8;
        int gp = (ghk * 37) >> 8;
        int kh = ghk - gp * 7;
        const f16x8* kp = (const f16x8*)(Kb + ((((size_t)(b * 8 + gp) * 38 + x + kh) * 38 + y + kwl) << 5));
        f16x8 bf = kp[quad];
#pragma unroll
        for (int Mt = 0; Mt < 2; ++Mt) {
            f32x4 d = {0.f, 0.f, 0.f, 0.f};
            d = MFMA16(qf[Mt], bf, d);
            f16x4 rh = *(const f16x4*)(RHT + ghk * 36 + Mt * 16 + quad * 4);
            f16x4 rw = *(const f16x4*)(RWT + (gp * 8 + kwl) * 36 + Mt * 16 + quad * 4);
#pragma unroll
            for (int r = 0; r < 4; ++r) {
                float s = d[r] + (float)rh[r] + (float)rw[r];
                s = mask7 ? -1e30f : s;
                fsum[Mt][r] += __expf(s);
            }
        }
    }
#pragma unroll
    for (int dlt = 1; dlt < 16; dlt <<= 1) {
#pragma unroll
        for (int m = 0; m < 2; ++m)
#pragma unroll
            for (int r = 0; r < 4; ++r) fsum[m][r] += __shfl_xor(fsum[m][r], dlt);
    }
    float inv[2][4];
#pragma unroll
    for (int m = 0; m < 2; ++m)
#pragma unroll
        for (int r = 0; r < 4; ++r) inv[m][r] = 1.0f / fsum[m][r];

    // ---- pass 2: normalized + head-summed A8, packed into regs ----
    f16x2 apk[28];
#pragma unroll
    for (int nt = 0; nt < 28; ++nt) {
        int ghk = nt * 2 + p8;
        int gp = (ghk * 37) >> 8;
        int kh = ghk - gp * 7;
        const f16x8* kp = (const f16x8*)(Kb + ((((size_t)(b * 8 + gp) * 38 + x + kh) * 38 + y + kwl) << 5));
        f16x8 bf = kp[quad];
        float a8[2];
#pragma unroll
        for (int Mt = 0; Mt < 2; ++Mt) {
            f32x4 d = {0.f, 0.f, 0.f, 0.f};
            d = MFMA16(qf[Mt], bf, d);
            f16x4 rh = *(const f16x4*)(RHT + ghk * 36 + Mt * 16 + quad * 4);
            f16x4 rw = *(const f16x4*)(RWT + (gp * 8 + kwl) * 36 + Mt * 16 + quad * 4);
            float acc = 0.f;
#pragma unroll
            for (int r = 0; r < 4; ++r) {
                float s = d[r] + (float)rh[r] + (float)rw[r];
                s = mask7 ? -1e30f : s;
                acc = fmaf(__expf(s), inv[Mt][r], acc);
            }
            a8[Mt] = acc;
        }
        f16x2 pk;
        pk.x = (f16)a8[0];
        pk.y = (f16)a8[1];
        apk[nt] = pk;
    }
    __syncthreads();  // rel-table reads done before aliasing as Apr
#pragma unroll
    for (int nt = 0; nt < 28; ++nt) {
        Apr[quad * 456 + nt * 16 + l15] = apk[nt].x;
        Apr[(4 + quad) * 456 + nt * 16 + l15] = apk[nt].y;
    }
    __syncthreads();

    // ---- PV: D[g][c] = A8 · V  (V fragments streamed from global Vt) ----
    f32x4 acc[2];
    acc[0] = (f32x4){0.f, 0.f, 0.f, 0.f};
    acc[1] = (f32x4){0.f, 0.f, 0.f, 0.f};
    for (int ks = 0; ks < 14; ++ks) {
        f16x8 af = *(const f16x8*)(Apr + l15 * 456 + ks * 32 + quad * 8);
        int ghk = ks * 4 + quad;
        int gp = (ghk * 37) >> 8;
        int kh = ghk - gp * 7;
#pragma unroll
        for (int t2 = 0; t2 < 2; ++t2) {
            int c = t2 * 16 + l15;
            const float* vp = Vt + ((((size_t)(b * 8 + gp) * 32 + c) * 38 + x + kh)) * 40 + y;
            f32x4u v0 = *(const f32x4u*)vp;
            f32x4u v1 = *(const f32x4u*)(vp + 4);
            f16x8 bf;
            bf[0] = (f16)v0[0]; bf[1] = (f16)v0[1]; bf[2] = (f16)v0[2]; bf[3] = (f16)v0[3];
            bf[4] = (f16)v1[0]; bf[5] = (f16)v1[1]; bf[6] = (f16)v1[2]; bf[7] = (f16)v1[3];
            acc[t2] = MFMA16(af, bf, acc[t2]);
        }
    }
    if (quad < 2) {
#pragma unroll
        for (int t2 = 0; t2 < 2; ++t2)
#pragma unroll
            for (int r = 0; r < 4; ++r) {
                int g = quad * 4 + r;
                out[(((size_t)(b * 8 + g) * 32 + x) * 32 + y) * 32 + t2 * 16 + l15] = acc[t2][r];
            }
    }
}

// ---------------------------------------------------------------------------
extern "C" void kernel_launch(void* const* d_in, const int* in_sizes, int n_in,
                              void* d_out, int out_size, void* d_ws, size_t ws_size,
                              hipStream_t stream) {
    const float* x     = (const float*)d_in[0];
    const float* wq    = (const float*)d_in[1];
    const float* bq    = (const float*)d_in[2];
    const float* wk    = (const float*)d_in[3];
    const float* bk    = (const float*)d_in[4];
    const float* wv    = (const float*)d_in[5];
    const float* bv    = (const float*)d_in[6];
    const float* rel_h = (const float*)d_in[7];
    const float* rel_w = (const float*)d_in[8];
    float* out = (float*)d_out;

    // ws layout (bytes), all 16B-aligned:
    //   Qb16 : 4096*1024*2          = 8,388,608
    //   Kb16 : 4*8*38*38*32*2       = 2,957,312
    //   Vt32 : 4*8*32*38*40*4       = 6,225,920
    //   relhA: 64*32*2              = 4,096
    //   relwA: 64*32*2              = 4,096
    unsigned char* ws = (unsigned char*)d_ws;
    f16*   Qb    = (f16*)ws;
    f16*   Kb    = (f16*)(ws + 8388608);
    float* Vt    = (float*)(ws + 8388608 + 2957312);
    f16*   relhA = (f16*)(ws + 8388608 + 2957312 + 6225920);
    f16*   relwA = (f16*)(ws + 8388608 + 2957312 + 6225920 + 4096);

    hipLaunchKernelGGL(prep_kernel, dim3(1), dim3(256), 0, stream,
                       rel_h, rel_w, relhA, relwA);
    hipLaunchKernelGGL(q_kernel, dim3(4 * 8 * 32), dim3(256), 0, stream,
                       x, wq, bq, Qb);
    hipLaunchKernelGGL(kv_kernel, dim3(4 * 8 * 38), dim3(256), 0, stream,
                       x, wk, bk, wv, bv, Kb, Vt);
    hipLaunchKernelGGL(attn_kernel, dim3(4096), dim3(64), 0, stream,
                       Qb, Kb, Vt, relhA, relwA, out);
}

// Round 4
// 148.243 us; speedup vs baseline: 2.2100x; 1.1640x over previous
//
#include <hip/hip_runtime.h>
#include <math.h>

typedef _Float16 f16;
typedef _Float16 f16x8 __attribute__((ext_vector_type(8)));
typedef __bf16 bf16x8 __attribute__((ext_vector_type(8)));
typedef float f32x4 __attribute__((ext_vector_type(4)));
typedef float f32x4u __attribute__((ext_vector_type(4), aligned(4)));

#define MFMA_F16(a, b, c)  __builtin_amdgcn_mfma_f32_16x16x32_f16(a, b, c, 0, 0, 0)
#define MFMA_BF16(a, b, c) __builtin_amdgcn_mfma_f32_16x16x32_bf16(a, b, c, 0, 0, 0)

// ---------------------------------------------------------------------------
// Fused producer. Blocks 0..1215: (b,g,hp) rows -> Q,K,V via f16 MFMA.
// Block 1216: build relp[448 keys][32 c] f16 (rel folded into K channels).
// Layouts: Qb f16 [pos][qi*32+c]; Kb f16 [b][g][hp][wp][c];
//          Vt f32 [b][g][c][hp][wp(40; 38,39 zeroed)].
// ---------------------------------------------------------------------------
__global__ __launch_bounds__(256) void produce_kernel(
    const float* __restrict__ x,
    const float* __restrict__ wq, const float* __restrict__ bq,
    const float* __restrict__ wk, const float* __restrict__ bk,
    const float* __restrict__ wv, const float* __restrict__ bv,
    const float* __restrict__ rel_h, const float* __restrict__ rel_w,
    f16* __restrict__ Qb, f16* __restrict__ Kb, float* __restrict__ Vt,
    f16* __restrict__ relp) {
    int bid = blockIdx.x;
    int t = threadIdx.x;

    if (bid == 1216) {  // rel' table: key=(gp*7+kh)*8+kw, c channel
        for (int idx = t; idx < 448 * 32; idx += 256) {
            int c = idx & 31, key = idx >> 5;
            int kw = key & 7, ghk = key >> 3;
            int gp = (ghk * 37) >> 8;
            int kh = ghk - gp * 7;
            float v = 0.f;
            if (kw < 7)
                v = (c < 16) ? rel_h[c * 56 + gp * 7 + kh]
                             : rel_w[(c - 16) * 56 + gp * 7 + kw];
            relp[idx] = (f16)v;
        }
        return;
    }

    int hp = bid % 38, g = (bid / 38) & 7, b = bid / 304;
    bool hin = (hp >= 3 && hp < 35);
    size_t kvbase = (size_t)(b * 8 + g);

    if (!hin) {  // pure-bias row (x padding)
        for (int idx = t; idx < 38 * 32; idx += 256) {
            int wp = idx >> 5, c = idx & 31;
            Kb[((kvbase * 38 + hp) * 38 + wp) * 32 + c] = (f16)bk[g * 32 + c];
        }
        for (int idx = t; idx < 40 * 32; idx += 256) {
            int wp = idx >> 5, c = idx & 31;
            Vt[((kvbase * 32 + c) * 38 + hp) * 40 + wp] =
                (wp < 38) ? bv[g * 32 + c] : 0.f;
        }
        return;
    }

    int h = hp - 3;
    __shared__ __align__(16) f16 xTl[32 * 40];    // [w][ic]
    __shared__ __align__(16) f16 wqhl[128 * 40];  // [oc][ic]
    __shared__ __align__(16) f16 wkhl[32 * 40];
    __shared__ __align__(16) f16 wvhl[32 * 40];

    for (int idx = t; idx < 1024; idx += 256) {
        int ic = idx >> 5, w = idx & 31;
        xTl[w * 40 + ic] = (f16)x[(((size_t)b * 256 + g * 32 + ic) * 32 + h) * 32 + w];
    }
    for (int idx = t; idx < 4096; idx += 256) {
        int oc = idx >> 5, ic = idx & 31;
        wqhl[oc * 40 + ic] = (f16)wq[((size_t)g * 128 + oc) * 32 + ic];
    }
    for (int idx = t; idx < 1024; idx += 256) {
        int c = idx >> 5, ic = idx & 31;
        wkhl[c * 40 + ic] = (f16)wk[((size_t)g * 32 + c) * 32 + ic];
        wvhl[c * 40 + ic] = (f16)wv[((size_t)g * 32 + c) * 32 + ic];
    }
    __syncthreads();

    int l15 = t & 15, quad = (t >> 4) & 3, wave = t >> 6;

    // A fragments (x^T): rows = w
    f16x8 a0 = *(const f16x8*)(xTl + l15 * 40 + quad * 8);
    f16x8 a1 = *(const f16x8*)(xTl + (16 + l15) * 40 + quad * 8);

    // ---- Q: this wave covers Nt = wave*2 + {0,1} ----
#pragma unroll
    for (int i = 0; i < 2; ++i) {
        int Nt = wave * 2 + i;
        f16x8 bfrag = *(const f16x8*)(wqhl + (Nt * 16 + l15) * 40 + quad * 8);
        float bias = bq[g * 128 + Nt * 16 + l15];
#pragma unroll
        for (int Mt = 0; Mt < 2; ++Mt) {
            f32x4 d = {0.f, 0.f, 0.f, 0.f};
            d = MFMA_F16(Mt ? a1 : a0, bfrag, d);
#pragma unroll
            for (int r = 0; r < 4; ++r) {
                int w = Mt * 16 + quad * 4 + r;
                Qb[(size_t)((b * 32 + h) * 32 + w) * 1024 + g * 128 + Nt * 16 + l15] =
                    (f16)(d[r] + bias);
            }
        }
    }

    // ---- K/V: wave -> (sel = K/V, Nth) ----
    {
        int sel = wave & 1, Nth = wave >> 1;
        const f16* wl = sel ? wvhl : wkhl;
        f16x8 bfrag = *(const f16x8*)(wl + (Nth * 16 + l15) * 40 + quad * 8);
        float bias = (sel ? bv : bk)[g * 32 + Nth * 16 + l15];
        int c = Nth * 16 + l15;
#pragma unroll
        for (int Mt = 0; Mt < 2; ++Mt) {
            f32x4 d = {0.f, 0.f, 0.f, 0.f};
            d = MFMA_F16(Mt ? a1 : a0, bfrag, d);
#pragma unroll
            for (int r = 0; r < 4; ++r) {
                int wp = Mt * 16 + quad * 4 + r + 3;
                float v = d[r] + bias;
                if (!sel)
                    Kb[((kvbase * 38 + hp) * 38 + wp) * 32 + c] = (f16)v;
                else
                    Vt[((kvbase * 32 + c) * 38 + hp) * 40 + wp] = v;
            }
        }
    }

    // ---- border wp (0..2, 35..37) bias + Vt pad cols ----
    for (int idx = t; idx < 192; idx += 256) {
        int wi = idx >> 5, c = idx & 31;
        int wp = (wi < 3) ? wi : (32 + wi);
        Kb[((kvbase * 38 + hp) * 38 + wp) * 32 + c] = (f16)bk[g * 32 + c];
        Vt[((kvbase * 32 + c) * 38 + hp) * 40 + wp] = bv[g * 32 + c];
    }
    if (t < 64) {
        int c = t >> 1, pad = 38 + (t & 1);
        Vt[((kvbase * 32 + c) * 38 + hp) * 40 + pad] = 0.f;
    }
}

// ---------------------------------------------------------------------------
// Fused MFMA attention: one wave per position, single-pass softmax.
// Keys chunked in 2 halves (gp 0-3 / 4-7), 224 keys each (kw=7 masked).
// P = exp(s) unnormalized bf16 in LDS [32 qi][232]; PV per-head bf16 MFMA;
// 1/sum + head-sum in epilogue (lane-local: g=quad, head=reg).
// LDS 14,848 B -> 10 blocks/CU.
// ---------------------------------------------------------------------------
__global__ __launch_bounds__(64, 4) void attn_kernel(
    const f16* __restrict__ Qb, const f16* __restrict__ Kb,
    const float* __restrict__ Vt, const f16* __restrict__ relp,
    float* __restrict__ out) {
    int bid = blockIdx.x;
    int pid = (bid & 7) * 512 + (bid >> 3);  // XCD-locality swizzle
    int y = pid & 31, x = (pid >> 5) & 31, b = pid >> 10;

    __shared__ __align__(16) __bf16 Pl[32 * 232];

    int t = threadIdx.x;
    int l15 = t & 15, quad = t >> 4, kwl = t & 7, p8 = (t >> 3) & 1;
    bool mask7 = (kwl == 7);

    // Q fragments: A[m=qi][k=c]
    f16x8 qf[2];
    {
        const f16* qp = Qb + (size_t)pid * 1024;
        qf[0] = *(const f16x8*)(qp + l15 * 32 + quad * 8);
        qf[1] = *(const f16x8*)(qp + (16 + l15) * 32 + quad * 8);
    }

    float fsum[2][4];
#pragma unroll
    for (int m = 0; m < 2; ++m)
#pragma unroll
        for (int r = 0; r < 4; ++r) fsum[m][r] = 0.f;

    f32x4 acc[2][2];
#pragma unroll
    for (int m = 0; m < 2; ++m)
#pragma unroll
        for (int n = 0; n < 2; ++n) acc[m][n] = (f32x4){0.f, 0.f, 0.f, 0.f};

    int yk = y + kwl;
    if (yk > 37) yk = 37;  // masked column: clamp load (value discarded)

    for (int chunk = 0; chunk < 2; ++chunk) {
        // ---- scores + exp + bf16 P store ----
#pragma unroll 2
        for (int nt = 0; nt < 14; ++nt) {
            int ghk = chunk * 28 + nt * 2 + p8;
            int gp = (ghk * 37) >> 8;
            int kh = ghk - gp * 7;
            f16x8 kb = *(const f16x8*)(
                Kb + ((((size_t)(b * 8 + gp) * 38 + x + kh) * 38 + yk) << 5) + quad * 8);
            f16x8 rp = *(const f16x8*)(relp + (size_t)(ghk * 8 + kwl) * 32 + quad * 8);
            kb += rp;  // K' = K + rel'
#pragma unroll
            for (int Mt = 0; Mt < 2; ++Mt) {
                f32x4 d = {0.f, 0.f, 0.f, 0.f};
                d = MFMA_F16(qf[Mt], kb, d);
#pragma unroll
                for (int r = 0; r < 4; ++r) {
                    float e = __expf(d[r]);
                    e = mask7 ? 0.f : e;
                    fsum[Mt][r] += e;
                    Pl[(Mt * 16 + quad * 4 + r) * 232 + nt * 16 + l15] = (__bf16)e;
                }
            }
        }
        __syncthreads();

        // ---- PV accumulate: D[qi][c] += P · V ----
#pragma unroll 2
        for (int ks = 0; ks < 7; ++ks) {
            int ghk = chunk * 28 + ks * 4 + quad;
            int gp = (ghk * 37) >> 8;
            int kh = ghk - gp * 7;
            bf16x8 af[2];
#pragma unroll
            for (int Mt = 0; Mt < 2; ++Mt)
                af[Mt] = *(const bf16x8*)(Pl + (Mt * 16 + l15) * 232 + ks * 32 + quad * 8);
#pragma unroll
            for (int t2 = 0; t2 < 2; ++t2) {
                const float* vp =
                    Vt + (((size_t)(b * 8 + gp) * 32 + t2 * 16 + l15) * 38 + x + kh) * 40 + y;
                f32x4u v0 = *(const f32x4u*)vp;
                f32x4u v1 = *(const f32x4u*)(vp + 4);
                bf16x8 bf;
                bf[0] = (__bf16)v0[0]; bf[1] = (__bf16)v0[1];
                bf[2] = (__bf16)v0[2]; bf[3] = (__bf16)v0[3];
                bf[4] = (__bf16)v1[0]; bf[5] = (__bf16)v1[1];
                bf[6] = (__bf16)v1[2]; bf[7] = (__bf16)v1[3];
#pragma unroll
                for (int Mt = 0; Mt < 2; ++Mt)
                    acc[Mt][t2] = MFMA_BF16(af[Mt], bf, acc[Mt][t2]);
            }
        }
        __syncthreads();  // Pl reused next chunk
    }

    // ---- epilogue: row sums across the 16 key-columns, 1/sum, head-sum ----
#pragma unroll
    for (int dlt = 1; dlt < 16; dlt <<= 1)
#pragma unroll
        for (int m = 0; m < 2; ++m)
#pragma unroll
            for (int r = 0; r < 4; ++r) fsum[m][r] += __shfl_xor(fsum[m][r], dlt);

    float inv[2][4];
#pragma unroll
    for (int m = 0; m < 2; ++m)
#pragma unroll
        for (int r = 0; r < 4; ++r) inv[m][r] = 1.0f / fsum[m][r];

#pragma unroll
    for (int Mt = 0; Mt < 2; ++Mt)
#pragma unroll
        for (int t2 = 0; t2 < 2; ++t2) {
            float o = 0.f;
#pragma unroll
            for (int r = 0; r < 4; ++r) o = fmaf(acc[Mt][t2][r], inv[Mt][r], o);
            int g = Mt * 4 + quad;  // qi = Mt*16+quad*4+r -> g lane-local, head=r
            out[(((size_t)(b * 8 + g) * 32 + x) * 32 + y) * 32 + t2 * 16 + l15] = o;
        }
}

// ---------------------------------------------------------------------------
extern "C" void kernel_launch(void* const* d_in, const int* in_sizes, int n_in,
                              void* d_out, int out_size, void* d_ws, size_t ws_size,
                              hipStream_t stream) {
    const float* x     = (const float*)d_in[0];
    const float* wq    = (const float*)d_in[1];
    const float* bq    = (const float*)d_in[2];
    const float* wk    = (const float*)d_in[3];
    const float* bk    = (const float*)d_in[4];
    const float* wv    = (const float*)d_in[5];
    const float* bv    = (const float*)d_in[6];
    const float* rel_h = (const float*)d_in[7];
    const float* rel_w = (const float*)d_in[8];
    float* out = (float*)d_out;

    // ws layout (bytes):
    //   Qb  f16 : 4096*1024*2     = 8,388,608
    //   Kb  f16 : 4*8*38*38*32*2  = 2,957,312
    //   Vt  f32 : 4*8*32*38*40*4  = 6,225,920
    //   relp f16: 448*32*2        = 28,672
    unsigned char* ws = (unsigned char*)d_ws;
    f16*   Qb   = (f16*)ws;
    f16*   Kb   = (f16*)(ws + 8388608);
    float* Vt   = (float*)(ws + 8388608 + 2957312);
    f16*   relp = (f16*)(ws + 8388608 + 2957312 + 6225920);

    hipLaunchKernelGGL(produce_kernel, dim3(1217), dim3(256), 0, stream,
                       x, wq, bq, wk, bk, wv, bv, rel_h, rel_w, Qb, Kb, Vt, relp);
    hipLaunchKernelGGL(attn_kernel, dim3(4096), dim3(64), 0, stream,
                       Qb, Kb, Vt, relp, out);
}

// Round 5
// 126.576 us; speedup vs baseline: 2.5883x; 1.1712x over previous
//
#include <hip/hip_runtime.h>
#include <math.h>

typedef _Float16 f16;
typedef _Float16 f16x8 __attribute__((ext_vector_type(8)));
typedef __bf16 bf16x8 __attribute__((ext_vector_type(8)));
typedef __bf16 bf16x8a4 __attribute__((ext_vector_type(8), aligned(4)));
typedef float f32x4 __attribute__((ext_vector_type(4)));

#define MFMA_F16(a, b, c)  __builtin_amdgcn_mfma_f32_16x16x32_f16(a, b, c, 0, 0, 0)
#define MFMA_BF16(a, b, c) __builtin_amdgcn_mfma_f32_16x16x32_bf16(a, b, c, 0, 0, 0)

// ---------------------------------------------------------------------------
// Fused producer. Blocks 0..1215: (b,g,hp) rows -> Q,K,V via f16 MFMA.
// Weights load straight to register fragments (no LDS staging); only x^T is
// staged in LDS. Block 1216 builds relp.
// Layouts: Qb f16 [pos][g*128 + head*32 + c]; Kb f16 [b][g][hp][wp][c];
//          VtA bf16 [b][g][c][hp][idx=wp (40)]; VtB same but idx = wp-1
//          (wp-shifted copy so attn loads are 4B-aligned for any y).
// ---------------------------------------------------------------------------
__global__ __launch_bounds__(256) void produce_kernel(
    const float* __restrict__ x,
    const float* __restrict__ wq, const float* __restrict__ bq,
    const float* __restrict__ wk, const float* __restrict__ bk,
    const float* __restrict__ wv, const float* __restrict__ bv,
    const float* __restrict__ rel_h, const float* __restrict__ rel_w,
    f16* __restrict__ Qb, f16* __restrict__ Kb,
    __bf16* __restrict__ VtA, __bf16* __restrict__ VtB,
    f16* __restrict__ relp) {
    int bid = blockIdx.x;
    int t = threadIdx.x;

    if (bid == 1216) {  // rel' table: key=(gp*7+kh)*8+kw, channel c
        for (int idx = t; idx < 448 * 32; idx += 256) {
            int c = idx & 31, key = idx >> 5;
            int kw = key & 7, ghk = key >> 3;
            int gp = (ghk * 37) >> 8;
            int kh = ghk - gp * 7;
            float v = 0.f;
            if (kw < 7)
                v = (c < 16) ? rel_h[c * 56 + gp * 7 + kh]
                             : rel_w[(c - 16) * 56 + gp * 7 + kw];
            relp[idx] = (f16)v;
        }
        return;
    }

    int hp = bid % 38, g = (bid / 38) & 7, b = bid / 304;
    bool hin = (hp >= 3 && hp < 35);
    size_t kvbase = (size_t)(b * 8 + g);

    if (!hin) {  // pure-bias row (h padding)
        for (int idx = t; idx < 38 * 32; idx += 256) {
            int wp = idx >> 5, c = idx & 31;
            Kb[((kvbase * 38 + hp) * 38 + wp) * 32 + c] = (f16)bk[g * 32 + c];
        }
        for (int idx = t; idx < 40 * 32; idx += 256) {
            int i = idx >> 5, c = idx & 31;
            size_t vo = ((kvbase * 32 + c) * 38 + hp) * 40;
            __bf16 bb = (__bf16)bv[g * 32 + c];
            VtA[vo + i] = (i < 38) ? bb : (__bf16)0.f;
            VtB[vo + i] = (i < 37) ? bb : (__bf16)0.f;  // idx i = wp i+1
        }
        return;
    }

    int h = hp - 3;
    __shared__ __align__(16) f16 xTl[32 * 40];  // [w][ic], stride 40

    {   // stage x^T (each thread one float4 along w)
        int ic = t >> 3, w = (t & 7) * 4;
        float4 xv = *(const float4*)(x + (((size_t)b * 256 + g * 32 + ic) * 32 + h) * 32 + w);
        xTl[(w + 0) * 40 + ic] = (f16)xv.x;
        xTl[(w + 1) * 40 + ic] = (f16)xv.y;
        xTl[(w + 2) * 40 + ic] = (f16)xv.z;
        xTl[(w + 3) * 40 + ic] = (f16)xv.w;
    }
    __syncthreads();

    int l15 = t & 15, quad = (t >> 4) & 3, wave = t >> 6;

    f16x8 a0 = *(const f16x8*)(xTl + l15 * 40 + quad * 8);
    f16x8 a1 = *(const f16x8*)(xTl + (16 + l15) * 40 + quad * 8);

    // ---- Q: wave covers Nt = wave*2 + {0,1} ----
#pragma unroll
    for (int i = 0; i < 2; ++i) {
        int Nt = wave * 2 + i;
        const float4* wp4 = (const float4*)(wq + ((size_t)g * 128 + Nt * 16 + l15) * 32 + quad * 8);
        float4 u0 = wp4[0], u1 = wp4[1];
        f16x8 bfrag;
        bfrag[0] = (f16)u0.x; bfrag[1] = (f16)u0.y; bfrag[2] = (f16)u0.z; bfrag[3] = (f16)u0.w;
        bfrag[4] = (f16)u1.x; bfrag[5] = (f16)u1.y; bfrag[6] = (f16)u1.z; bfrag[7] = (f16)u1.w;
        float bias = bq[g * 128 + Nt * 16 + l15];
#pragma unroll
        for (int Mt = 0; Mt < 2; ++Mt) {
            f32x4 d = {0.f, 0.f, 0.f, 0.f};
            d = MFMA_F16(Mt ? a1 : a0, bfrag, d);
#pragma unroll
            for (int r = 0; r < 4; ++r) {
                int w = Mt * 16 + quad * 4 + r;
                Qb[(size_t)((b * 32 + h) * 32 + w) * 1024 + g * 128 + Nt * 16 + l15] =
                    (f16)(d[r] + bias);
            }
        }
    }

    // ---- K/V: wave -> (sel, Nth) ----
    {
        int sel = wave & 1, Nth = wave >> 1;
        const float* wsrc = sel ? wv : wk;
        const float4* wp4 = (const float4*)(wsrc + ((size_t)g * 32 + Nth * 16 + l15) * 32 + quad * 8);
        float4 u0 = wp4[0], u1 = wp4[1];
        f16x8 bfrag;
        bfrag[0] = (f16)u0.x; bfrag[1] = (f16)u0.y; bfrag[2] = (f16)u0.z; bfrag[3] = (f16)u0.w;
        bfrag[4] = (f16)u1.x; bfrag[5] = (f16)u1.y; bfrag[6] = (f16)u1.z; bfrag[7] = (f16)u1.w;
        float bias = (sel ? bv : bk)[g * 32 + Nth * 16 + l15];
        int c = Nth * 16 + l15;
#pragma unroll
        for (int Mt = 0; Mt < 2; ++Mt) {
            f32x4 d = {0.f, 0.f, 0.f, 0.f};
            d = MFMA_F16(Mt ? a1 : a0, bfrag, d);
#pragma unroll
            for (int r = 0; r < 4; ++r) {
                int wp = Mt * 16 + quad * 4 + r + 3;
                float v = d[r] + bias;
                if (!sel) {
                    Kb[((kvbase * 38 + hp) * 38 + wp) * 32 + c] = (f16)v;
                } else {
                    size_t vo = ((kvbase * 32 + c) * 38 + hp) * 40;
                    VtA[vo + wp] = (__bf16)v;
                    VtB[vo + wp - 1] = (__bf16)v;
                }
            }
        }
    }

    // ---- wp borders (bias) + zero pads ----
    for (int idx = t; idx < 192; idx += 256) {
        int wi = idx >> 5, c = idx & 31;
        int wp = (wi < 3) ? wi : (32 + wi);  // {0,1,2,35,36,37}
        Kb[((kvbase * 38 + hp) * 38 + wp) * 32 + c] = (f16)bk[g * 32 + c];
        size_t vo = ((kvbase * 32 + c) * 38 + hp) * 40;
        __bf16 bb = (__bf16)bv[g * 32 + c];
        VtA[vo + wp] = bb;
        if (wp >= 1) VtB[vo + wp - 1] = bb;
    }
    for (int idx = t; idx < 160; idx += 256) {  // VtA idx 38,39; VtB idx 37,38,39
        int c = idx / 5, j = idx % 5;
        size_t vo = ((kvbase * 32 + c) * 38 + hp) * 40;
        if (j < 2) VtA[vo + 38 + j] = (__bf16)0.f;
        else       VtB[vo + 35 + j] = (__bf16)0.f;
    }
}

// ---------------------------------------------------------------------------
// MFMA attention: one wave per position, NO barriers (Pl is wave-private).
// 4 chunks of 2 groups (gp = chunk*2 + p8); per chunk 112 keys + 16 pad cols.
// Pl bf16 [32 qi][136] (8704 B -> 18 blocks/CU); pad cols 112..127 zeroed.
// PV B-fragments: single aligned(4) 16B bf16 load from VtA/VtB (y-parity).
// ---------------------------------------------------------------------------
__global__ __launch_bounds__(64, 4) void attn_kernel(
    const f16* __restrict__ Qb, const f16* __restrict__ Kb,
    const __bf16* __restrict__ VtA, const __bf16* __restrict__ VtB,
    const f16* __restrict__ relp, float* __restrict__ out) {
    int bid = blockIdx.x;
    int pid = (bid & 7) * 512 + (bid >> 3);  // XCD-locality swizzle
    int y = pid & 31, x = (pid >> 5) & 31, b = pid >> 10;

    __shared__ __align__(16) __bf16 Pl[32 * 136];

    int t = threadIdx.x;
    int l15 = t & 15, quad = t >> 4, kwl = t & 7, p8 = (t >> 3) & 1;
    bool mask7 = (kwl == 7);

    {   // zero pad cols 112..127 (read by masked kh=7 PV fragments)
        int row = t >> 1, off = 112 + (t & 1) * 8;
        *(uint4*)(Pl + row * 136 + off) = (uint4){0u, 0u, 0u, 0u};
    }

    // Q fragments: A[m=qi][k=c]
    f16x8 qf[2];
    {
        const f16* qp = Qb + (size_t)pid * 1024;
        qf[0] = *(const f16x8*)(qp + l15 * 32 + quad * 8);
        qf[1] = *(const f16x8*)(qp + (16 + l15) * 32 + quad * 8);
    }

    float fsum[2][4];
#pragma unroll
    for (int m = 0; m < 2; ++m)
#pragma unroll
        for (int r = 0; r < 4; ++r) fsum[m][r] = 0.f;

    f32x4 acc[2][2];
#pragma unroll
    for (int m = 0; m < 2; ++m)
#pragma unroll
        for (int n = 0; n < 2; ++n) acc[m][n] = (f32x4){0.f, 0.f, 0.f, 0.f};

    int yk = y + kwl;
    if (yk > 37) yk = 37;  // masked column: clamp (value discarded)
    const __bf16* __restrict__ Vsel = (y & 1) ? VtB : VtA;
    int yv = y & ~1;

    for (int chunk = 0; chunk < 4; ++chunk) {
        // ---- scores + exp + bf16 P store (gp = chunk*2 + p8, kh 0..6) ----
        int gp = chunk * 2 + p8;
        const f16* kbp = Kb + ((((size_t)(b * 8 + gp) * 38 + x) * 38 + yk) << 5) + quad * 8;
        const f16* rpp = relp + (size_t)(gp * 7 * 8 + kwl) * 32 + quad * 8;
#pragma unroll
        for (int kh = 0; kh < 7; ++kh) {
            f16x8 kb = *(const f16x8*)kbp;
            f16x8 rp = *(const f16x8*)rpp;
            kbp += 38 * 32;
            rpp += 256;
            kb += rp;  // K' = K + rel'
#pragma unroll
            for (int Mt = 0; Mt < 2; ++Mt) {
                f32x4 d = {0.f, 0.f, 0.f, 0.f};
                d = MFMA_F16(qf[Mt], kb, d);
#pragma unroll
                for (int r = 0; r < 4; ++r) {
                    float e = __expf(d[r]);
                    e = mask7 ? 0.f : e;
                    fsum[Mt][r] += e;
                    Pl[(Mt * 16 + quad * 4 + r) * 136 + kh * 16 + l15] = (__bf16)e;
                }
            }
        }

        // ---- PV accumulate: D[qi][c] += P · V ----
        int gpv = chunk * 2 + (quad & 1);
        int qh = quad >> 1;
#pragma unroll
        for (int ks = 0; ks < 4; ++ks) {
            bf16x8 af0 = *(const bf16x8*)(Pl + l15 * 136 + ks * 32 + quad * 8);
            bf16x8 af1 = *(const bf16x8*)(Pl + (16 + l15) * 136 + ks * 32 + quad * 8);
            int kh = 2 * ks + qh;
            int khc = (kh > 6) ? 6 : kh;  // masked fragment reads zeros from Pl
#pragma unroll
            for (int t2 = 0; t2 < 2; ++t2) {
                const __bf16* vp =
                    Vsel + (((size_t)(b * 8 + gpv) * 32 + t2 * 16 + l15) * 38 + x + khc) * 40 + yv;
                bf16x8a4 bv8 = *(const bf16x8a4*)vp;
                acc[0][t2] = MFMA_BF16(af0, (bf16x8)bv8, acc[0][t2]);
                acc[1][t2] = MFMA_BF16(af1, (bf16x8)bv8, acc[1][t2]);
            }
        }
    }

    // ---- epilogue: reduce fsum over 16 key-cols, 1/sum, head-sum ----
#pragma unroll
    for (int dlt = 1; dlt < 16; dlt <<= 1)
#pragma unroll
        for (int m = 0; m < 2; ++m)
#pragma unroll
            for (int r = 0; r < 4; ++r) fsum[m][r] += __shfl_xor(fsum[m][r], dlt);

    float inv[2][4];
#pragma unroll
    for (int m = 0; m < 2; ++m)
#pragma unroll
        for (int r = 0; r < 4; ++r) inv[m][r] = 1.0f / fsum[m][r];

#pragma unroll
    for (int Mt = 0; Mt < 2; ++Mt)
#pragma unroll
        for (int t2 = 0; t2 < 2; ++t2) {
            float o = 0.f;
#pragma unroll
            for (int r = 0; r < 4; ++r) o = fmaf(acc[Mt][t2][r], inv[Mt][r], o);
            int g = Mt * 4 + quad;  // qi = Mt*16+quad*4+r -> g lane-local, head = r
            out[(((size_t)(b * 8 + g) * 32 + x) * 32 + y) * 32 + t2 * 16 + l15] = o;
        }
}

// ---------------------------------------------------------------------------
extern "C" void kernel_launch(void* const* d_in, const int* in_sizes, int n_in,
                              void* d_out, int out_size, void* d_ws, size_t ws_size,
                              hipStream_t stream) {
    const float* x     = (const float*)d_in[0];
    const float* wq    = (const float*)d_in[1];
    const float* bq    = (const float*)d_in[2];
    const float* wk    = (const float*)d_in[3];
    const float* bk    = (const float*)d_in[4];
    const float* wv    = (const float*)d_in[5];
    const float* bv    = (const float*)d_in[6];
    const float* rel_h = (const float*)d_in[7];
    const float* rel_w = (const float*)d_in[8];
    float* out = (float*)d_out;

    // ws layout (bytes):
    //   Qb  f16 : 4096*1024*2        = 8,388,608
    //   Kb  f16 : 4*8*38*38*32*2     = 2,957,312
    //   VtA bf16: 4*8*32*38*40*2     = 3,112,960
    //   VtB bf16: 3,112,960
    //   relp f16: 448*32*2           = 28,672
    unsigned char* ws = (unsigned char*)d_ws;
    f16*    Qb   = (f16*)ws;
    f16*    Kb   = (f16*)(ws + 8388608);
    __bf16* VtA  = (__bf16*)(ws + 8388608 + 2957312);
    __bf16* VtB  = (__bf16*)(ws + 8388608 + 2957312 + 3112960);
    f16*    relp = (f16*)(ws + 8388608 + 2957312 + 3112960 + 3112960);

    hipLaunchKernelGGL(produce_kernel, dim3(1217), dim3(256), 0, stream,
                       x, wq, bq, wk, bk, wv, bv, rel_h, rel_w, Qb, Kb, VtA, VtB, relp);
    hipLaunchKernelGGL(attn_kernel, dim3(4096), dim3(64), 0, stream,
                       Qb, Kb, VtA, VtB, relp, out);
}